// Round 14
// baseline (141.776 us; speedup 1.0000x reference)
//
#include <hip/hip_runtime.h>
#include <cstdio>
#include <cmath>

#define TSEQ 2048
#define CDIM 1024
#define NBATCH 4

typedef float f32x4 __attribute__((ext_vector_type(4)));
typedef __bf16 bf16x8 __attribute__((ext_vector_type(8)));
typedef unsigned short u16;
typedef u16 u16x8 __attribute__((ext_vector_type(8)));
typedef u16 u16x4 __attribute__((ext_vector_type(4)));

// f32 -> bf16 round-to-nearest-even
__device__ __forceinline__ u16 f2bf(float f) {
  unsigned u = __builtin_bit_cast(unsigned, f);
  unsigned r = (u + 0x7FFFu + ((u >> 16) & 1u)) >> 16;
  return (u16)r;
}

// async global->LDS, 16B per lane; lds base wave-uniform (HW adds lane*16)
__device__ __forceinline__ void gload_lds16(const void* g, void* l) {
  __builtin_amdgcn_global_load_lds(
      (__attribute__((address_space(1))) void*)g,
      (__attribute__((address_space(3))) void*)l, 16, 0, 0);
}

// 3-bit XOR swizzle for 128B-row LDS tiles (row = byte>>7): colblk ^= row&7.
// Proven conflict-free on HW (R5..R13: SQ_LDS_BANK_CONFLICT ~ 0).
#define SWZ2(b_) ((b_) ^ ((((b_) >> 7) & 7) << 4))

// ---------------------------------------------------------------------------
// R13 4-wave 128x128 BK=64 core (scores/pv — unchanged).
// ---------------------------------------------------------------------------
__device__ __forceinline__ void gemm128(
    const u16* __restrict__ A, const u16* __restrict__ B,
    int lda, int ldb, int m0, int n0, int nT,
    char* smem, f32x4 acc[4][4])
{
  u16* Ab = (u16*)smem;               // [2][128*64]
  u16* Bb = (u16*)(smem + 32768);     // [2][128*64]
  const int tid = threadIdx.x, w = tid >> 6, l = tid & 63;
  const int wr = w >> 1, wc = w & 1;
  const int frow = l & 15, fko = l >> 4;
  const int srow = l >> 3;
  const int scol = ((l & 7) * 8) ^ (((l >> 3) & 7) << 3);

  const u16* gA = A + (size_t)(m0 + w * 32 + srow) * lda + scol;
  const u16* gB = B + (size_t)(n0 + w * 32 + srow) * ldb + scol;

  auto stageA = [&](int t) {
    if (t >= nT) return;
    const u16* s = gA + t * 64;
    u16* d = Ab + (t & 1) * 8192 + w * 2048;
    gload_lds16(s, d);
    gload_lds16(s + (size_t)8 * lda, d + 512);
    gload_lds16(s + (size_t)16 * lda, d + 1024);
    gload_lds16(s + (size_t)24 * lda, d + 1536);
  };
  auto stageB = [&](int t) {
    if (t >= nT) return;
    const u16* s = gB + t * 64;
    u16* d = Bb + (t & 1) * 8192 + w * 2048;
    gload_lds16(s, d);
    gload_lds16(s + (size_t)8 * ldb, d + 512);
    gload_lds16(s + (size_t)16 * ldb, d + 1024);
    gload_lds16(s + (size_t)24 * ldb, d + 1536);
  };

#define AOFF(mf, ks) SWZ2(((wr * 64 + (mf) * 16 + frow) * 128 + (ks) * 64 + fko * 16))
#define BOFF(nf, ks) SWZ2(((wc * 64 + (nf) * 16 + frow) * 128 + (ks) * 64 + fko * 16))

  bf16x8 s0A[4][2], s0B[4][2], s1A[4][2], s1B[4][2];

#define RD(S, T) do {                                                         \
    const char* Ab_ = (const char*)Ab + ((T) & 1) * 16384;                    \
    const char* Bb_ = (const char*)Bb + ((T) & 1) * 16384;                    \
    _Pragma("unroll") for (int nf = 0; nf < 4; ++nf)                          \
    _Pragma("unroll") for (int ks = 0; ks < 2; ++ks)                          \
        S##B[nf][ks] = *(const bf16x8*)(Bb_ + BOFF(nf, ks));                  \
    _Pragma("unroll") for (int mf = 0; mf < 4; ++mf)                          \
    _Pragma("unroll") for (int ks = 0; ks < 2; ++ks)                          \
        S##A[mf][ks] = *(const bf16x8*)(Ab_ + AOFF(mf, ks));                  \
  } while (0)

#define MM(S) do {                                                            \
    __builtin_amdgcn_s_setprio(1);                                            \
    _Pragma("unroll") for (int ks = 0; ks < 2; ++ks)                          \
    _Pragma("unroll") for (int mf = 0; mf < 4; ++mf)                          \
    _Pragma("unroll") for (int nf = 0; nf < 4; ++nf)                          \
        acc[mf][nf] = __builtin_amdgcn_mfma_f32_16x16x32_bf16(                \
            S##A[mf][ks], S##B[nf][ks], acc[mf][nf], 0, 0, 0);                \
    __builtin_amdgcn_s_setprio(0);                                            \
  } while (0)

#define WIN(T, CUR, NXT) do {                                                 \
    if ((T) < nT - 2) asm volatile("s_waitcnt vmcnt(8)" ::: "memory");        \
    else              asm volatile("s_waitcnt vmcnt(0)" ::: "memory");        \
    __builtin_amdgcn_s_barrier();                                             \
    __builtin_amdgcn_sched_barrier(0);                                        \
    if ((T) + 1 < nT) RD(NXT, (T) + 1);                                       \
    MM(CUR);                                                                  \
    asm volatile("s_waitcnt lgkmcnt(0)" ::: "memory");                        \
    __builtin_amdgcn_s_barrier();                                             \
    __builtin_amdgcn_sched_barrier(0);                                        \
    stageB((T) + 3);                                                          \
    stageA((T) + 3);                                                          \
  } while (0)

  stageB(0); stageA(0); stageB(1); stageA(1);
  asm volatile("s_waitcnt vmcnt(8)" ::: "memory");
  __builtin_amdgcn_s_barrier();
  RD(s0, 0);
  asm volatile("s_waitcnt lgkmcnt(0)" ::: "memory");
  __builtin_amdgcn_s_barrier();
  __builtin_amdgcn_sched_barrier(0);
  stageB(2); stageA(2);

#pragma unroll 1
  for (int t = 0; t < nT; t += 2) {
    WIN(t, s0, s1);
    WIN(t + 1, s1, s0);
  }
#undef WIN
#undef MM
#undef RD
#undef AOFF
#undef BOFF
}

#define ACC_ZERO4(acc)                                  \
  _Pragma("unroll") for (int m_ = 0; m_ < 4; ++m_)      \
  _Pragma("unroll") for (int n_ = 0; n_ < 4; ++n_)      \
      acc[m_][n_] = (f32x4){0.f, 0.f, 0.f, 0.f};

// ---------------------------------------------------------------------------
// cvt: 8 elems/thread, bf16x8 16B stores
__global__ void __launch_bounds__(256) k_cvt_all(
    const float* __restrict__ x, const float* __restrict__ Wk,
    const float* __restrict__ Wq, const float* __restrict__ Wv,
    u16* __restrict__ xb, u16* __restrict__ wb)
{
  const int NX8 = (NBATCH * TSEQ * CDIM) / 8;
  const int NW8 = (CDIM * CDIM) / 8;
  int g = blockIdx.x * 256 + threadIdx.x;
  const float* src; u16* dst; int i;
  if (g < NX8) { src = x; dst = xb; i = g; }
  else {
    int g2 = g - NX8;
    int w = g2 / NW8; i = g2 - w * NW8;
    src = (w == 0) ? Wk : (w == 1) ? Wq : Wv;
    dst = wb + (size_t)w * CDIM * CDIM;
  }
  float4 v0 = ((const float4*)src)[2 * i];
  float4 v1 = ((const float4*)src)[2 * i + 1];
  u16x8 o;
  o[0] = f2bf(v0.x); o[1] = f2bf(v0.y); o[2] = f2bf(v0.z); o[3] = f2bf(v0.w);
  o[4] = f2bf(v1.x); o[5] = f2bf(v1.y); o[6] = f2bf(v1.z); o[7] = f2bf(v1.w);
  *(u16x8*)(dst + (size_t)8 * i) = o;
}

// ---------------------------------------------------------------------------
// QKV 8-phase 256x256 (R4 structure + FIXED 3-bit swizzle + per-phase lgkm).
// A = xb [8192][1024], B = wb [3072][1024] K-major. 384 blocks = 8 XCD x 48.
// 512 thr = 8 waves (2M x 4N), wave tile 128x64 (24KB LDS-read / 64 MFMA —
// 2x the MFMA-per-byte of the 64x64 wave tile; LDS-BW ceiling ~85%).
// LDS 128 KiB: A/B x 2buf x 2half x [128 rows][64 cols] bf16 (128B rows).
// Half-tile stream per K-tile T: A1(T+1) [ph0], B0,B1,A0(T+2) [ph1..3];
// vmcnt(6) at each tile's phase 3, vmcnt(0) at T=14. Per-phase lgkmcnt(0)
// right after the barrier bounds the stage-vs-read window (m201 discipline).
// ---------------------------------------------------------------------------
__global__ void __launch_bounds__(512) k_gemm_qkv8(
    const u16* __restrict__ xb, const u16* __restrict__ wb,
    u16* __restrict__ kb, u16* __restrict__ qb, u16* __restrict__ vt)
{
  extern __shared__ char smem[];
  u16* Ab = (u16*)smem;             // [2 buf][2 half][128*64]
  u16* Bb = (u16*)(smem + 65536);

  const int id = blockIdx.x;
  const int xcd = id & 7, loc = id >> 3;        // 384 = 8 x 48
  const int mt = xcd * 4 + (loc & 3);           // 4 m-panels/XCD (2MB, L2-fit)
  const int nt = loc >> 2;                      // 0..11
  const int m0 = mt * 256;
  const int n0g = nt * 256;                     // in [0,3072)

  const int tid = threadIdx.x;
  const int w = tid >> 6, l = tid & 63;
  const int wr = w >> 2, wc = w & 3;
  const int frow = l & 15, fko = l >> 4;
  const int bh = wc >> 1;                        // B half this wave reads
  const int srow = l >> 3;
  const int scol = ((l & 7) * 8) ^ (((l >> 3) & 7) * 8);  // inverse-swz src col

  f32x4 acc[8][4];
#pragma unroll
  for (int m_ = 0; m_ < 8; ++m_)
#pragma unroll
    for (int n_ = 0; n_ < 4; ++n_) acc[m_][n_] = (f32x4){0.f, 0.f, 0.f, 0.f};

  auto stageA = [&](int t, int half) {
    const u16* g = xb + (size_t)(m0 + half * 128 + w * 16 + srow) * CDIM + t * 64 + scol;
    u16* lb = Ab + ((t & 1) * 2 + half) * 8192 + w * 1024;
    gload_lds16(g, lb);
    gload_lds16(g + (size_t)8 * CDIM, lb + 512);
  };
  auto stageB = [&](int t, int half) {
    const u16* g = wb + (size_t)(n0g + half * 128 + w * 16 + srow) * CDIM + t * 64 + scol;
    u16* lb = Bb + ((t & 1) * 2 + half) * 8192 + w * 1024;
    gload_lds16(g, lb);
    gload_lds16(g + (size_t)8 * CDIM, lb + 512);
  };
  auto stageH = [&](int j) {
    if (j >= 64) return;
    const int t = j >> 2, kind = j & 3;
    if (kind == 0) stageB(t, 0);
    else if (kind == 1) stageB(t, 1);
    else if (kind == 2) stageA(t, 0);
    else stageA(t, 1);
  };

#define AOFF8(mf, ks) SWZ2((((mf) * 16 + frow) * 128 + (ks) * 64 + fko * 16))
#define BOFF8(nf, ks) SWZ2((((wc & 1) * 64 + (nf) * 16 + frow) * 128 + (ks) * 64 + fko * 16))

#define PHASE(Q, JS, VM) do {                                                 \
    bf16x8 afr[2][2];                                                         \
    _Pragma("unroll") for (int mm = 0; mm < 2; ++mm)                          \
    _Pragma("unroll") for (int ks = 0; ks < 2; ++ks)                          \
        afr[mm][ks] = *(const bf16x8*)(Abase + AOFF8(2 * (Q) + mm, ks));      \
    __builtin_amdgcn_sched_barrier(0);                                        \
    stageH(JS);                                                               \
    __builtin_amdgcn_s_barrier();                                             \
    asm volatile("s_waitcnt lgkmcnt(0)" ::: "memory");                        \
    __builtin_amdgcn_sched_barrier(0);                                        \
    __builtin_amdgcn_s_setprio(1);                                            \
    _Pragma("unroll") for (int ks = 0; ks < 2; ++ks)                          \
    _Pragma("unroll") for (int mm = 0; mm < 2; ++mm)                          \
    _Pragma("unroll") for (int nf = 0; nf < 4; ++nf)                          \
        acc[2 * (Q) + mm][nf] = __builtin_amdgcn_mfma_f32_16x16x32_bf16(      \
            afr[mm][ks], bfr[nf][ks], acc[2 * (Q) + mm][nf], 0, 0, 0);        \
    __builtin_amdgcn_s_setprio(0);                                            \
    if ((VM) == 6) asm volatile("s_waitcnt vmcnt(6)" ::: "memory");           \
    else if ((VM) == 0) asm volatile("s_waitcnt vmcnt(0)" ::: "memory");      \
    __builtin_amdgcn_s_barrier();                                             \
  } while (0)

#define KTILE(T, VM) do {                                                     \
    const char* Abase = (const char*)Ab + (((T) & 1) * 2 + wr) * 16384;       \
    const char* Bbase = (const char*)Bb + (((T) & 1) * 2 + bh) * 16384;       \
    bf16x8 bfr[4][2];                                                         \
    _Pragma("unroll") for (int nf = 0; nf < 4; ++nf)                          \
    _Pragma("unroll") for (int ks = 0; ks < 2; ++ks)                          \
        bfr[nf][ks] = *(const bf16x8*)(Bbase + BOFF8(nf, ks));                \
    PHASE(0, 4 * (T) + 7, -1);                                                \
    PHASE(1, 4 * (T) + 8, -1);                                                \
    PHASE(2, 4 * (T) + 9, -1);                                                \
    PHASE(3, 4 * (T) + 10, VM);                                               \
  } while (0)

  // prologue: stage H0..H6 (tile0 complete + 3 halves ahead)
#pragma unroll
  for (int j = 0; j < 7; ++j) stageH(j);
  asm volatile("s_waitcnt vmcnt(6)" ::: "memory");
  __builtin_amdgcn_s_barrier();

#pragma unroll 1
  for (int i = 0; i < 7; ++i) { KTILE(2 * i, 6); KTILE(2 * i + 1, 6); }
  KTILE(14, 0);
  KTILE(15, -1);

#undef PHASE
#undef KTILE
#undef AOFF8
#undef BOFF8

  // epilogue (direct stores; R4-proven mapping)
  const int z = n0g >> 10;
  if (z < 2) {
    u16* outp = (z == 0) ? kb : qb;
    const float scale = (z == 1) ? 0.03125f : 1.0f;
    const int nc0 = (n0g & 1023) + wc * 64 + frow;
    const int r0 = m0 + wr * 128 + fko * 4;
#pragma unroll
    for (int mf = 0; mf < 8; ++mf)
#pragma unroll
      for (int nf = 0; nf < 4; ++nf) {
        const int r = r0 + mf * 16;
        const int c = nc0 + nf * 16;
#pragma unroll
        for (int j2 = 0; j2 < 4; ++j2)
          outp[(size_t)(r + j2) * CDIM + c] = f2bf(acc[mf][nf][j2] * scale);
      }
  } else {
    // V: store transposed directly — j runs along t (contiguous 4 u16 = 8B)
    const int b = m0 >> 11;
    const int tloc0 = (m0 & 2047) + wr * 128 + fko * 4;
    const int c0 = (n0g - 2048) + wc * 64 + frow;
#pragma unroll
    for (int mf = 0; mf < 8; ++mf)
#pragma unroll
      for (int nf = 0; nf < 4; ++nf) {
        u16x4 o;
        o[0] = f2bf(acc[mf][nf][0]); o[1] = f2bf(acc[mf][nf][1]);
        o[2] = f2bf(acc[mf][nf][2]); o[3] = f2bf(acc[mf][nf][3]);
        *(u16x4*)(vt + ((size_t)b * CDIM + c0 + nf * 16) * TSEQ + tloc0 + mf * 16) = o;
      }
  }
}

// ---------------------------------------------------------------------------
// Scores (R13, unchanged): S = Q K^T -> P_unnorm = exp(S) bf16 + rowsums.
__global__ void __launch_bounds__(256, 2) k_gemm_scores_t(
    const u16* __restrict__ qb, const u16* __restrict__ kb,
    u16* __restrict__ pb, float* __restrict__ rs)
{
  extern __shared__ char smem[];
  const int id = blockIdx.x;
  const int sw = (id & 7) * 68 + (id >> 3);
  const int b = sw / 136;
  const int wq = sw - b * 136;
  int y = (int)((sqrtf(8.f * wq + 1.f) - 1.f) * 0.5f);
  while ((y + 1) * (y + 2) / 2 <= wq) ++y;
  while (y * (y + 1) / 2 > wq) --y;
  const int xt = wq - y * (y + 1) / 2;
  const int m0 = y * 128, n0 = xt * 128;

  const u16* A = qb + (size_t)b * TSEQ * CDIM;
  const u16* B = kb + (size_t)b * TSEQ * CDIM;
  u16* P = pb + (size_t)b * TSEQ * TSEQ;

  f32x4 acc[4][4];
  ACC_ZERO4(acc);
  gemm128(A, B, CDIM, CDIM, m0, n0, 16, smem, acc);

  const int tid = threadIdx.x, w = tid >> 6, l = tid & 63;
  const int wr = w >> 1, wc = w & 1;
  const int frow = l & 15, fko = l >> 4;
  u16* tile = (u16*)smem;                     // [128][136] u16
  float* rowpart = (float*)(smem + 34816);    // [128][2] f32

  __syncthreads();
#pragma unroll
  for (int mf = 0; mf < 4; ++mf) {
#pragma unroll
    for (int j = 0; j < 4; ++j) {
      const int rloc = wr * 64 + mf * 16 + fko * 4 + j;
      const int rglob = m0 + rloc;
      float p4 = 0.f;
#pragma unroll
      for (int nf = 0; nf < 4; ++nf) {
        const int cl = wc * 64 + nf * 16 + frow;
        const int c = n0 + cl;
        float e = (c <= rglob) ? __expf(acc[mf][nf][j]) : 0.f;
        p4 += e;
        tile[rloc * 136 + cl] = f2bf(e);
      }
#pragma unroll
      for (int d = 1; d < 16; d <<= 1) p4 += __shfl_xor(p4, d);
      if (frow == 0) rowpart[rloc * 2 + wc] = p4;
    }
  }
  __syncthreads();
  u16* dst = P + (size_t)m0 * TSEQ + n0;
#pragma unroll
  for (int it = 0; it < 8; ++it) {
    const int idx = it * 256 + tid;
    const int r = idx >> 4, ch = idx & 15;
    *(bf16x8*)(dst + (size_t)r * TSEQ + ch * 8) =
        *(const bf16x8*)(tile + r * 136 + ch * 8);
  }
  if (tid < 128)
    rs[((size_t)b * 16 + xt) * TSEQ + m0 + tid] =
        rowpart[tid * 2] + rowpart[tid * 2 + 1];
}

// ---------------------------------------------------------------------------
// PV (R13, unchanged): O = (P @ V) * inv_rowsum; complementary-mt balance.
__global__ void __launch_bounds__(256, 2) k_gemm_pv_t(
    const u16* __restrict__ pb, const u16* __restrict__ vt,
    const float* __restrict__ rs, float* __restrict__ out)
{
  extern __shared__ char smem[];
  const int id = blockIdx.x;
  const int n = id & 7, loc = id >> 3;
  int b, mt;
  if (loc < 32) { mt = 15 - (loc & 15); b = loc >> 4; }
  else          { mt = loc & 15;        b = 2 + ((loc - 32) >> 4); }
  const int m0 = mt * 128, n0 = n * 128;
  const int nT = 2 * (mt + 1);

  const u16* A = pb + (size_t)b * TSEQ * TSEQ;
  const u16* B = vt + (size_t)b * CDIM * TSEQ;
  float* O = out + (size_t)b * TSEQ * CDIM;

  f32x4 acc[4][4];
  ACC_ZERO4(acc);
  gemm128(A, B, TSEQ, TSEQ, m0, n0, nT, smem, acc);

  const int tid = threadIdx.x, w = tid >> 6, l = tid & 63;
  const int wr = w >> 1, wc = w & 1;
  const int frow = l & 15, fko = l >> 4;

  __syncthreads();
  float* sinv = (float*)smem;  // [128]
  if (tid < 128) {
    float s = 0.f;
    const float* p = rs + (size_t)b * 16 * TSEQ + m0 + tid;
    for (int x = 0; x <= mt; ++x) s += p[(size_t)x * TSEQ];
    sinv[tid] = 1.f / s;
  }
  __syncthreads();

#pragma unroll
  for (int mf = 0; mf < 4; ++mf) {
    const int rloc = wr * 64 + mf * 16 + fko * 4;
    const int r = m0 + rloc;
    const float4 iv = *(const float4*)&sinv[rloc];
    const float ivj[4] = {iv.x, iv.y, iv.z, iv.w};
#pragma unroll
    for (int nf = 0; nf < 4; ++nf) {
      const int c = n0 + wc * 64 + nf * 16 + frow;
#pragma unroll
      for (int j = 0; j < 4; ++j)
        O[(size_t)(r + j) * CDIM + c] = acc[mf][nf][j] * ivj[j];
    }
  }
}

// ---------------------------------------------------------------------------
extern "C" void kernel_launch(void* const* d_in, const int* in_sizes, int n_in,
                              void* d_out, int out_size, void* d_ws, size_t ws_size,
                              hipStream_t stream) {
  const float* x  = (const float*)d_in[0];
  const float* Wk = (const float*)d_in[1];
  const float* Wq = (const float*)d_in[2];
  const float* Wv = (const float*)d_in[3];
  float* out = (float*)d_out;

  const size_t M = (size_t)NBATCH * TSEQ;

  size_t off = 0;
  auto alloc = [&](size_t bytes) {
    void* p = (char*)d_ws + off;
    off += (bytes + 255) & ~(size_t)255;
    return p;
  };
  u16* xb = (u16*)alloc(M * CDIM * 2);
  u16* wb = (u16*)alloc(3ull * CDIM * CDIM * 2);
  u16* qb = (u16*)alloc(M * CDIM * 2);
  u16* kb = (u16*)alloc(M * CDIM * 2);
  u16* vt = (u16*)alloc(M * CDIM * 2);
  u16* pbuf = (u16*)alloc((size_t)NBATCH * TSEQ * TSEQ * 2);
  float* rs = (float*)alloc((size_t)NBATCH * 16 * TSEQ * 4);
  if (off > ws_size) {
    fprintf(stderr, "kernel_launch: ws too small: need %zu, have %zu\n", off, ws_size);
    return;
  }

  const int NX8 = (NBATCH * TSEQ * CDIM) / 8;
  const int NW8 = (CDIM * CDIM) / 8;
  const int cvtBlocks = (NX8 + 3 * NW8) / 256;

  static_cast<void>(hipFuncSetAttribute(
      reinterpret_cast<const void*>(k_gemm_qkv8),
      hipFuncAttributeMaxDynamicSharedMemorySize, 131072));
  static_cast<void>(hipFuncSetAttribute(
      reinterpret_cast<const void*>(k_gemm_scores_t),
      hipFuncAttributeMaxDynamicSharedMemorySize, 65536));
  static_cast<void>(hipFuncSetAttribute(
      reinterpret_cast<const void*>(k_gemm_pv_t),
      hipFuncAttributeMaxDynamicSharedMemorySize, 65536));

  k_cvt_all<<<cvtBlocks, 256, 0, stream>>>(x, Wk, Wq, Wv, xb, wb);
  k_gemm_qkv8<<<384, 512, 131072, stream>>>(xb, wb, kb, qb, vt);
  k_gemm_scores_t<<<544, 256, 65536, stream>>>(qb, kb, pbuf, rs);
  k_gemm_pv_t<<<512, 256, 65536, stream>>>(pbuf, vt, rs, out);
}

// Round 15
// 128.669 us; speedup vs baseline: 1.1019x; 1.1019x over previous
//
#include <hip/hip_runtime.h>
#include <cstdio>
#include <cmath>

#define TSEQ 2048
#define CDIM 1024
#define NBATCH 4

typedef float f32x4 __attribute__((ext_vector_type(4)));
typedef __bf16 bf16x8 __attribute__((ext_vector_type(8)));
typedef unsigned short u16;
typedef u16 u16x8 __attribute__((ext_vector_type(8)));

// f32 -> bf16 round-to-nearest-even
__device__ __forceinline__ u16 f2bf(float f) {
  unsigned u = __builtin_bit_cast(unsigned, f);
  unsigned r = (u + 0x7FFFu + ((u >> 16) & 1u)) >> 16;
  return (u16)r;
}

// async global->LDS, 16B per lane; lds base wave-uniform (HW adds lane*16)
__device__ __forceinline__ void gload_lds16(const void* g, void* l) {
  __builtin_amdgcn_global_load_lds(
      (__attribute__((address_space(1))) void*)g,
      (__attribute__((address_space(3))) void*)l, 16, 0, 0);
}

// ---------------------------------------------------------------------------
// 4-wave 128x128 BK=64 core — R13 (best measured): reads(t+1) overlap MFMA(t)
// via register double-buffered fragments (sets s0/s1, static indexing).
// Window t: vmcnt(8|0) -> barrier -> [RD(t+1) || MFMA(t)] -> lgkmcnt(0)
//           -> barrier -> stage(t+3).
// Race-free invariants (R11 lineage):
//  - stage(x) writes buf[x&1] only after lgkmcnt(0)+barrier proves all
//    waves' reads of tile x-2 (same buffer) completed (frags live in regs).
//  - RD(t+1) requires stage(t+1) landed: head vmcnt(8) leaves only
//    stage(t+2) (8 newest) in flight. At t >= nT-2 -> vmcnt(0).
// T2 3-bit XOR swizzle. nT even >= 2. LDS 64 KiB -> 2 blocks/CU (TLP).
// ---------------------------------------------------------------------------
#define SWZ2(b_) ((b_) ^ ((((b_) >> 7) & 7) << 4))

__device__ __forceinline__ void gemm128(
    const u16* __restrict__ A, const u16* __restrict__ B,
    int lda, int ldb, int m0, int n0, int nT,
    char* smem, f32x4 acc[4][4])
{
  u16* Ab = (u16*)smem;               // [2][128*64]
  u16* Bb = (u16*)(smem + 32768);     // [2][128*64]
  const int tid = threadIdx.x, w = tid >> 6, l = tid & 63;
  const int wr = w >> 1, wc = w & 1;
  const int frow = l & 15, fko = l >> 4;
  const int srow = l >> 3;
  const int scol = ((l & 7) * 8) ^ (((l >> 3) & 7) << 3);

  const u16* gA = A + (size_t)(m0 + w * 32 + srow) * lda + scol;
  const u16* gB = B + (size_t)(n0 + w * 32 + srow) * ldb + scol;

  auto stageA = [&](int t) {
    if (t >= nT) return;
    const u16* s = gA + t * 64;
    u16* d = Ab + (t & 1) * 8192 + w * 2048;
    gload_lds16(s, d);
    gload_lds16(s + (size_t)8 * lda, d + 512);
    gload_lds16(s + (size_t)16 * lda, d + 1024);
    gload_lds16(s + (size_t)24 * lda, d + 1536);
  };
  auto stageB = [&](int t) {
    if (t >= nT) return;
    const u16* s = gB + t * 64;
    u16* d = Bb + (t & 1) * 8192 + w * 2048;
    gload_lds16(s, d);
    gload_lds16(s + (size_t)8 * ldb, d + 512);
    gload_lds16(s + (size_t)16 * ldb, d + 1024);
    gload_lds16(s + (size_t)24 * ldb, d + 1536);
  };

#define AOFF(mf, ks) SWZ2(((wr * 64 + (mf) * 16 + frow) * 128 + (ks) * 64 + fko * 16))
#define BOFF(nf, ks) SWZ2(((wc * 64 + (nf) * 16 + frow) * 128 + (ks) * 64 + fko * 16))

  bf16x8 s0A[4][2], s0B[4][2], s1A[4][2], s1B[4][2];

#define RD(S, T) do {                                                         \
    const char* Ab_ = (const char*)Ab + ((T) & 1) * 16384;                    \
    const char* Bb_ = (const char*)Bb + ((T) & 1) * 16384;                    \
    _Pragma("unroll") for (int nf = 0; nf < 4; ++nf)                          \
    _Pragma("unroll") for (int ks = 0; ks < 2; ++ks)                          \
        S##B[nf][ks] = *(const bf16x8*)(Bb_ + BOFF(nf, ks));                  \
    _Pragma("unroll") for (int mf = 0; mf < 4; ++mf)                          \
    _Pragma("unroll") for (int ks = 0; ks < 2; ++ks)                          \
        S##A[mf][ks] = *(const bf16x8*)(Ab_ + AOFF(mf, ks));                  \
  } while (0)

#define MM(S) do {                                                            \
    __builtin_amdgcn_s_setprio(1);                                            \
    _Pragma("unroll") for (int ks = 0; ks < 2; ++ks)                          \
    _Pragma("unroll") for (int mf = 0; mf < 4; ++mf)                          \
    _Pragma("unroll") for (int nf = 0; nf < 4; ++nf)                          \
        acc[mf][nf] = __builtin_amdgcn_mfma_f32_16x16x32_bf16(                \
            S##A[mf][ks], S##B[nf][ks], acc[mf][nf], 0, 0, 0);                \
    __builtin_amdgcn_s_setprio(0);                                            \
  } while (0)

#define WIN(T, CUR, NXT) do {                                                 \
    if ((T) < nT - 2) asm volatile("s_waitcnt vmcnt(8)" ::: "memory");        \
    else              asm volatile("s_waitcnt vmcnt(0)" ::: "memory");        \
    __builtin_amdgcn_s_barrier();                                             \
    __builtin_amdgcn_sched_barrier(0);                                        \
    if ((T) + 1 < nT) RD(NXT, (T) + 1);                                       \
    MM(CUR);                                                                  \
    asm volatile("s_waitcnt lgkmcnt(0)" ::: "memory");                        \
    __builtin_amdgcn_s_barrier();                                             \
    __builtin_amdgcn_sched_barrier(0);                                        \
    stageB((T) + 3);                                                          \
    stageA((T) + 3);                                                          \
  } while (0)

  // prologue: stage tiles 0,1; read tile0 frags; then stage tile2 (buf0
  // safe: reads(0) drained by lgkmcnt(0)+barrier).
  stageB(0); stageA(0); stageB(1); stageA(1);
  asm volatile("s_waitcnt vmcnt(8)" ::: "memory");
  __builtin_amdgcn_s_barrier();
  RD(s0, 0);
  asm volatile("s_waitcnt lgkmcnt(0)" ::: "memory");
  __builtin_amdgcn_s_barrier();
  __builtin_amdgcn_sched_barrier(0);
  stageB(2); stageA(2);

#pragma unroll 1
  for (int t = 0; t < nT; t += 2) {
    WIN(t, s0, s1);
    WIN(t + 1, s1, s0);
  }
#undef WIN
#undef MM
#undef RD
#undef AOFF
#undef BOFF
}

#define ACC_ZERO4(acc)                                  \
  _Pragma("unroll") for (int m_ = 0; m_ < 4; ++m_)      \
  _Pragma("unroll") for (int n_ = 0; n_ < 4; ++n_)      \
      acc[m_][n_] = (f32x4){0.f, 0.f, 0.f, 0.f};

// ---------------------------------------------------------------------------
// cvt: 8 elems/thread, bf16x8 16B stores
__global__ void __launch_bounds__(256) k_cvt_all(
    const float* __restrict__ x, const float* __restrict__ Wk,
    const float* __restrict__ Wq, const float* __restrict__ Wv,
    u16* __restrict__ xb, u16* __restrict__ wb)
{
  const int NX8 = (NBATCH * TSEQ * CDIM) / 8;   // 1,048,576
  const int NW8 = (CDIM * CDIM) / 8;            // 131,072
  int g = blockIdx.x * 256 + threadIdx.x;
  const float* src; u16* dst; int i;
  if (g < NX8) { src = x; dst = xb; i = g; }
  else {
    int g2 = g - NX8;
    int w = g2 / NW8; i = g2 - w * NW8;
    src = (w == 0) ? Wk : (w == 1) ? Wq : Wv;
    dst = wb + (size_t)w * CDIM * CDIM;
  }
  float4 v0 = ((const float4*)src)[2 * i];
  float4 v1 = ((const float4*)src)[2 * i + 1];
  u16x8 o;
  o[0] = f2bf(v0.x); o[1] = f2bf(v0.y); o[2] = f2bf(v0.z); o[3] = f2bf(v0.w);
  o[4] = f2bf(v1.x); o[5] = f2bf(v1.y); o[6] = f2bf(v1.z); o[7] = f2bf(v1.w);
  *(u16x8*)(dst + (size_t)8 * i) = o;
}

// ---------------------------------------------------------------------------
// QKV: A = xb [8192][1024], B = wb [3072][1024]. 1536 blocks = 8 XCD x 192.
// z==0/1 (K,Q): LDS-repacked coalesced row-major writes (bf16x8).
// z==2 (V): transpose C-tile via LDS, write Vt[b][c][t] directly.
__global__ void __launch_bounds__(256, 2) k_gemm_qkv_t(
    const u16* __restrict__ xb, const u16* __restrict__ wb,
    u16* __restrict__ kb, u16* __restrict__ qb, u16* __restrict__ vt)
{
  extern __shared__ char smem[];
  const int id = blockIdx.x;
  const int xcd = id & 7, loc = id >> 3;
  const int mt = xcd * 8 + (loc & 7);        // 0..63
  const int nt = loc >> 3;                   // 0..23
  const int m0 = mt * 128, n0g = nt * 128;

  f32x4 acc[4][4];
  ACC_ZERO4(acc);
  gemm128(xb, wb, CDIM, CDIM, m0, n0g, 16, smem, acc);

  const int tid = threadIdx.x, w = tid >> 6, l = tid & 63;
  const int wr = w >> 1, wc = w & 1;
  const int frow = l & 15, fko = l >> 4;
  const int z = n0g >> 10;
  u16* tile = (u16*)smem;  // [128][136] u16 (16B-aligned rows)
  __syncthreads();          // fence: gemm LDS fully dead on all waves
  if (z < 2) {
    u16* outp = (z == 0) ? kb : qb;
    const float scale = (z == 1) ? 0.03125f : 1.0f;
#pragma unroll
    for (int mf = 0; mf < 4; ++mf)
#pragma unroll
      for (int nf = 0; nf < 4; ++nf) {
        const int rl = wr * 64 + mf * 16 + fko * 4;
        const int cl = wc * 64 + nf * 16 + frow;
#pragma unroll
        for (int j = 0; j < 4; ++j)
          tile[(rl + j) * 136 + cl] = f2bf(acc[mf][nf][j] * scale);
      }
    __syncthreads();
    u16* dst = outp + (size_t)m0 * CDIM + (n0g & 1023);
#pragma unroll
    for (int it = 0; it < 8; ++it) {
      const int idx = it * 256 + tid;      // 0..2047
      const int r = idx >> 4, ch = idx & 15;
      *(bf16x8*)(dst + (size_t)r * CDIM + ch * 8) =
          *(const bf16x8*)(tile + r * 136 + ch * 8);
    }
  } else {
    // V-transpose epilogue: tile[c][r]; coalesced b128 writes to Vt.
#pragma unroll
    for (int mf = 0; mf < 4; ++mf)
#pragma unroll
      for (int nf = 0; nf < 4; ++nf) {
        const int cl = wc * 64 + nf * 16 + frow;
        const int rl = wr * 64 + mf * 16 + fko * 4;
#pragma unroll
        for (int j = 0; j < 4; ++j)
          tile[cl * 136 + rl + j] = f2bf(acc[mf][nf][j]);
      }
    __syncthreads();
    const int b = m0 >> 11, t0 = m0 & 2047;
    const int c0g = n0g - 2048;
    u16* dst = vt + ((size_t)b * CDIM + c0g) * TSEQ + t0;
#pragma unroll
    for (int it = 0; it < 8; ++it) {
      const int idx = it * 256 + tid;      // 0..2047
      const int c = idx >> 4, ch = idx & 15;
      *(bf16x8*)(dst + (size_t)c * TSEQ + ch * 8) =
          *(const bf16x8*)(tile + c * 136 + ch * 8);
    }
  }
}

// ---------------------------------------------------------------------------
// Scores: S = Q K^T -> P_unnorm = exp(S) bf16 (max-free) + rowsum partials.
// 544 blocks = 8 XCD x 68; per-batch 16x16 lower triangle of 128 tiles.
__global__ void __launch_bounds__(256, 2) k_gemm_scores_t(
    const u16* __restrict__ qb, const u16* __restrict__ kb,
    u16* __restrict__ pb, float* __restrict__ rs)
{
  extern __shared__ char smem[];
  const int id = blockIdx.x;
  const int sw = (id & 7) * 68 + (id >> 3);
  const int b = sw / 136;
  const int wq = sw - b * 136;
  int y = (int)((sqrtf(8.f * wq + 1.f) - 1.f) * 0.5f);
  while ((y + 1) * (y + 2) / 2 <= wq) ++y;
  while (y * (y + 1) / 2 > wq) --y;
  const int xt = wq - y * (y + 1) / 2;
  const int m0 = y * 128, n0 = xt * 128;

  const u16* A = qb + (size_t)b * TSEQ * CDIM;
  const u16* B = kb + (size_t)b * TSEQ * CDIM;
  u16* P = pb + (size_t)b * TSEQ * TSEQ;

  f32x4 acc[4][4];
  ACC_ZERO4(acc);
  gemm128(A, B, CDIM, CDIM, m0, n0, 16, smem, acc);

  const int tid = threadIdx.x, w = tid >> 6, l = tid & 63;
  const int wr = w >> 1, wc = w & 1;
  const int frow = l & 15, fko = l >> 4;
  u16* tile = (u16*)smem;                     // [128][136] u16
  float* rowpart = (float*)(smem + 34816);    // [128][2] f32

  __syncthreads();  // fence: gemm LDS fully dead on all waves
#pragma unroll
  for (int mf = 0; mf < 4; ++mf) {
#pragma unroll
    for (int j = 0; j < 4; ++j) {
      const int rloc = wr * 64 + mf * 16 + fko * 4 + j;
      const int rglob = m0 + rloc;
      float p4 = 0.f;
#pragma unroll
      for (int nf = 0; nf < 4; ++nf) {
        const int cl = wc * 64 + nf * 16 + frow;
        const int c = n0 + cl;
        float e = (c <= rglob) ? __expf(acc[mf][nf][j]) : 0.f;
        p4 += e;
        tile[rloc * 136 + cl] = f2bf(e);
      }
#pragma unroll
      for (int d = 1; d < 16; d <<= 1) p4 += __shfl_xor(p4, d);
      if (frow == 0) rowpart[rloc * 2 + wc] = p4;
    }
  }
  __syncthreads();
  u16* dst = P + (size_t)m0 * TSEQ + n0;
#pragma unroll
  for (int it = 0; it < 8; ++it) {
    const int idx = it * 256 + tid;          // 0..2047
    const int r = idx >> 4, ch = idx & 15;
    *(bf16x8*)(dst + (size_t)r * TSEQ + ch * 8) =
        *(const bf16x8*)(tile + r * 136 + ch * 8);
  }
  if (tid < 128)
    rs[((size_t)b * 16 + xt) * TSEQ + m0 + tid] =
        rowpart[tid * 2] + rowpart[tid * 2 + 1];
}

// ---------------------------------------------------------------------------
// O = (P_unnorm @ V) * inv_rowsum; causal K-extent nT = 2*(mt+1).
// inv computed inline from rs. 512 blocks = 8 XCD x 64.
// Load-balance: loc and loc+32 carry complementary mt (sum 15).
__global__ void __launch_bounds__(256, 2) k_gemm_pv_t(
    const u16* __restrict__ pb, const u16* __restrict__ vt,
    const float* __restrict__ rs, float* __restrict__ out)
{
  extern __shared__ char smem[];
  const int id = blockIdx.x;
  const int n = id & 7, loc = id >> 3;   // loc 0..63
  int b, mt;
  if (loc < 32) { mt = 15 - (loc & 15); b = loc >> 4; }
  else          { mt = loc & 15;        b = 2 + ((loc - 32) >> 4); }
  const int m0 = mt * 128, n0 = n * 128;
  const int nT = 2 * (mt + 1);

  const u16* A = pb + (size_t)b * TSEQ * TSEQ;
  const u16* B = vt + (size_t)b * CDIM * TSEQ;
  float* O = out + (size_t)b * TSEQ * CDIM;

  f32x4 acc[4][4];
  ACC_ZERO4(acc);
  gemm128(A, B, TSEQ, TSEQ, m0, n0, nT, smem, acc);

  const int tid = threadIdx.x, w = tid >> 6, l = tid & 63;
  const int wr = w >> 1, wc = w & 1;
  const int frow = l & 15, fko = l >> 4;

  // inline inv_rowsum for this block's 128 rows
  __syncthreads();
  float* sinv = (float*)smem;  // [128]
  if (tid < 128) {
    float s = 0.f;
    const float* p = rs + (size_t)b * 16 * TSEQ + m0 + tid;
    for (int x = 0; x <= mt; ++x) s += p[(size_t)x * TSEQ];
    sinv[tid] = 1.f / s;
  }
  __syncthreads();

#pragma unroll
  for (int mf = 0; mf < 4; ++mf) {
    const int rloc = wr * 64 + mf * 16 + fko * 4;
    const int r = m0 + rloc;
    const float4 iv = *(const float4*)&sinv[rloc];
    const float ivj[4] = {iv.x, iv.y, iv.z, iv.w};
#pragma unroll
    for (int nf = 0; nf < 4; ++nf) {
      const int c = n0 + wc * 64 + nf * 16 + frow;
#pragma unroll
      for (int j = 0; j < 4; ++j)
        O[(size_t)(r + j) * CDIM + c] = acc[mf][nf][j] * ivj[j];
    }
  }
}

// ---------------------------------------------------------------------------
extern "C" void kernel_launch(void* const* d_in, const int* in_sizes, int n_in,
                              void* d_out, int out_size, void* d_ws, size_t ws_size,
                              hipStream_t stream) {
  const float* x  = (const float*)d_in[0];
  const float* Wk = (const float*)d_in[1];
  const float* Wq = (const float*)d_in[2];
  const float* Wv = (const float*)d_in[3];
  float* out = (float*)d_out;

  const size_t M = (size_t)NBATCH * TSEQ;

  size_t off = 0;
  auto alloc = [&](size_t bytes) {
    void* p = (char*)d_ws + off;
    off += (bytes + 255) & ~(size_t)255;
    return p;
  };
  u16* xb = (u16*)alloc(M * CDIM * 2);                 // x bf16 (live all of qkv)
  u16* wb = (u16*)alloc(3ull * CDIM * CDIM * 2);       // Wk|Wq|Wv bf16
  u16* qb = (u16*)alloc(M * CDIM * 2);                 // Q (pre-scaled)
  u16* kb = (u16*)alloc(M * CDIM * 2);                 // K
  u16* vt = (u16*)alloc(M * CDIM * 2);                 // Vt [B][C][T]
  u16* pbuf = (u16*)alloc((size_t)NBATCH * TSEQ * TSEQ * 2);   // P_unnorm bf16
  float* rs = (float*)alloc((size_t)NBATCH * 16 * TSEQ * 4);   // rowsum partials
  if (off > ws_size) {
    fprintf(stderr, "kernel_launch: ws too small: need %zu, have %zu\n", off, ws_size);
    return;
  }

  const int NX8 = (NBATCH * TSEQ * CDIM) / 8;
  const int NW8 = (CDIM * CDIM) / 8;
  const int cvtBlocks = (NX8 + 3 * NW8) / 256;

  static_cast<void>(hipFuncSetAttribute(
      reinterpret_cast<const void*>(k_gemm_qkv_t),
      hipFuncAttributeMaxDynamicSharedMemorySize, 65536));
  static_cast<void>(hipFuncSetAttribute(
      reinterpret_cast<const void*>(k_gemm_scores_t),
      hipFuncAttributeMaxDynamicSharedMemorySize, 65536));
  static_cast<void>(hipFuncSetAttribute(
      reinterpret_cast<const void*>(k_gemm_pv_t),
      hipFuncAttributeMaxDynamicSharedMemorySize, 65536));

  k_cvt_all<<<cvtBlocks, 256, 0, stream>>>(x, Wk, Wq, Wv, xb, wb);
  k_gemm_qkv_t<<<1536, 256, 65536, stream>>>(xb, wb, kb, qb, vt);
  k_gemm_scores_t<<<544, 256, 65536, stream>>>(qb, kb, pbuf, rs);
  k_gemm_pv_t<<<512, 256, 65536, stream>>>(pbuf, vt, rs, out);
}